// Round 1
// baseline (10141.177 us; speedup 1.0000x reference)
//
#include <hip/hip_runtime.h>
#include <math.h>

namespace {

constexpr int TPB  = 512;
constexpr int NB   = 256;   // batch
constexpr int NT   = 1000;  // time steps
constexpr int NX   = 64;    // state dim
constexpr int NS   = 4;     // control dim
constexpr int DIN  = 68;    // NX + NS
constexpr int HF   = 256;
constexpr int HG   = 128;
constexpr float DTC   = 0.01f;
constexpr float SIGMA = 0.1f;

__device__ __forceinline__ float tanh_fast(float x){
    // tanh(x) = 1 - 2/(e^{2x}+1); __expf handles +/-inf limits correctly.
    float e = __expf(2.0f * x);
    return 1.0f - 2.0f / (e + 1.0f);
}
__device__ __forceinline__ float softplus_f(float x){
    // numerically stable log(1+e^x)
    return fmaxf(x, 0.0f) + log1pf(__expf(-fabsf(x)));
}

// One workgroup (512 threads, 8 waves) integrates ONE batch element for all
// T steps. F-network weights are partitioned into per-thread register slices;
// Wg1 lives in LDS (touched once/step), Wg2 in registers.
__global__ __launch_bounds__(TPB, 2) void sde_rk4_kernel(
    const float* __restrict__ gIn, const float* __restrict__ gNz,
    const float* __restrict__ Wf1, const float* __restrict__ bf1,
    const float* __restrict__ Wf2, const float* __restrict__ bf2,
    const float* __restrict__ Wf3, const float* __restrict__ bf3,
    const float* __restrict__ Wg1, const float* __restrict__ bg1,
    const float* __restrict__ Wg2, const float* __restrict__ bg2,
    float* __restrict__ gOut)
{
    const int b = blockIdx.x;
    const int t = threadIdx.x;

    __shared__ __align__(16) float s_z[72];        // z[0:64]=state part, [64:68]=u
    __shared__ __align__(16) float s_hg[HG];
    __shared__ __align__(16) float s_h1[HF];
    __shared__ __align__(16) float s_h2[HF];
    __shared__ __align__(16) float s_kacc[NX];
    __shared__ __align__(16) float s_g[NX];
    __shared__ __align__(16) float s_X[NX];
    __shared__ __align__(16) float s_dw[2][NX];
    __shared__ float s_u[2][NS];
    __shared__ __align__(16) float s_part[16*260]; // partial-sum scratch (16.6 KB)
    __shared__ __align__(16) float s_wg1[DIN*HG];  // 34.8 KB
    __shared__ float s_bf1[HF], s_bf2[HF], s_bf3[NX], s_bg1[HG], s_bg2[NX];

    // ---- thread roles per layer ----
    const int colA  = t & (HF-1);          // L1: output column
    const int halfA = t >> 8;              // L1: k-slice 0 -> k[0,32), 1 -> k[32,68)
    const int jg  = t & 31, j0 = jg*8;     // L2: 8 output cols
    const int ksB = t >> 5, k0B = ksB*16;  // L2: 16-k slice
    const int colC = t & (NX-1);           // L3
    const int ksC = t >> 6, k0C = ksC*32;  // L3: 32-k slice
    const int colG1 = t & (HG-1);          // Lg1
    const int ksG1 = t >> 7;               // Lg1: slices of {16,16,16,20}
    const int colG2 = t & (NX-1);          // Lg2
    const int ksG2 = t >> 6, k0G2 = ksG2*16;

    // ---- register-resident weights (loaded once; ~18 us HBM chip-wide) ----
    float wf1r[36];
    if (halfA == 0) {
#pragma unroll
        for (int k = 0; k < 32; ++k) wf1r[k] = Wf1[k*HF + colA];
    } else {
#pragma unroll
        for (int k = 0; k < 36; ++k) wf1r[k] = Wf1[(32+k)*HF + colA];
    }
    float wf2r[16][8];
#pragma unroll
    for (int k = 0; k < 16; ++k) {
        const float4 a = *(const float4*)(Wf2 + (size_t)(k0B+k)*HF + j0);
        const float4 c = *(const float4*)(Wf2 + (size_t)(k0B+k)*HF + j0 + 4);
        wf2r[k][0]=a.x; wf2r[k][1]=a.y; wf2r[k][2]=a.z; wf2r[k][3]=a.w;
        wf2r[k][4]=c.x; wf2r[k][5]=c.y; wf2r[k][6]=c.z; wf2r[k][7]=c.w;
    }
    float wf3r[32];
#pragma unroll
    for (int k = 0; k < 32; ++k) wf3r[k] = Wf3[(k0C+k)*NX + colC];
    float wg2r[16];
#pragma unroll
    for (int k = 0; k < 16; ++k) wg2r[k] = Wg2[(k0G2+k)*NX + colG2];

    for (int i = t; i < DIN*HG; i += TPB) s_wg1[i] = Wg1[i];
    for (int i = t; i < HF;     i += TPB) { s_bf1[i] = bf1[i]; s_bf2[i] = bf2[i]; }
    if (t < HG) s_bg1[t] = bg1[t];
    if (t < NX) { s_bf3[t] = bf3[t]; s_bg2[t] = bg2[t]; }

    const float sq = sqrtf(DTC);
    const float* inB = gIn + (size_t)b*DIN*NT;
    const float* nzB = gNz + (size_t)b*NX*NT;
    float*      outB = gOut + (size_t)b*NX*NT;

    if (t < NX) {
        s_X[t]     = inB[(NS+t)*NT];     // X0 = Inputs[b, NS+t, 0]
        s_dw[0][t] = nzB[t*NT] * sq;
    }
    if (t < NS) s_u[0][t] = inB[t*NT];
    __syncthreads();

#pragma unroll 1
    for (int st = 0; st < NT; ++st) {
        const int p = st & 1;
        if (t < NX) s_z[t]    = s_X[t];
        if (t < NS) s_z[NX+t] = s_u[p][t];
        // prefetch next step's u / dW into registers (latency hidden under compute)
        float pf_dw = 0.0f, pf_u = 0.0f;
        if (st + 1 < NT) {
            if (t < NX) pf_dw = nzB[t*NT + st + 1] * sq;
            if (t < NS) pf_u  = inB[t*NT + st + 1];
        }
        __syncthreads();

        // ================= G network (uses z0 = [X,u]) =================
        {
            float a0=0.f, a1=0.f, a2=0.f, a3=0.f;
            if (ksG1 < 3) {
                const int kb = ksG1*16;
#pragma unroll
                for (int q = 0; q < 4; ++q) {
                    const float4 zv = *(const float4*)&s_z[kb + q*4];
                    const int k = kb + q*4;
                    a0 = fmaf(zv.x, s_wg1[(k+0)*HG + colG1], a0);
                    a1 = fmaf(zv.y, s_wg1[(k+1)*HG + colG1], a1);
                    a2 = fmaf(zv.z, s_wg1[(k+2)*HG + colG1], a2);
                    a3 = fmaf(zv.w, s_wg1[(k+3)*HG + colG1], a3);
                }
            } else {
#pragma unroll
                for (int q = 0; q < 5; ++q) {
                    const float4 zv = *(const float4*)&s_z[48 + q*4];
                    const int k = 48 + q*4;
                    a0 = fmaf(zv.x, s_wg1[(k+0)*HG + colG1], a0);
                    a1 = fmaf(zv.y, s_wg1[(k+1)*HG + colG1], a1);
                    a2 = fmaf(zv.z, s_wg1[(k+2)*HG + colG1], a2);
                    a3 = fmaf(zv.w, s_wg1[(k+3)*HG + colG1], a3);
                }
            }
            s_part[ksG1*132 + colG1] = (a0+a1)+(a2+a3);
        }
        __syncthreads();
        if (t < HG) {
            float s = s_bg1[t];
#pragma unroll
            for (int q = 0; q < 4; ++q) s += s_part[q*132 + t];
            s_hg[t] = tanh_fast(s);
        }
        __syncthreads();
        {
            float a0=0.f, a1=0.f, a2=0.f, a3=0.f;
#pragma unroll
            for (int q = 0; q < 4; ++q) {
                const float4 zv = *(const float4*)&s_hg[k0G2 + q*4];
                a0 = fmaf(zv.x, wg2r[q*4+0], a0);
                a1 = fmaf(zv.y, wg2r[q*4+1], a1);
                a2 = fmaf(zv.z, wg2r[q*4+2], a2);
                a3 = fmaf(zv.w, wg2r[q*4+3], a3);
            }
            s_part[ksG2*68 + colG2] = (a0+a1)+(a2+a3);
        }
        __syncthreads();
        if (t < NX) {
            float s = s_bg2[t];
#pragma unroll
            for (int q = 0; q < 8; ++q) s += s_part[q*68 + t];
            s_g[t] = SIGMA * softplus_f(s);
        }
        __syncthreads();

        // ================= RK4: four F evaluations =================
#pragma unroll 1
        for (int ev = 0; ev < 4; ++ev) {
            // ---- L1: z(68) -> h1(256)
            {
                float a0=0.f, a1=0.f, a2=0.f, a3=0.f;
                if (halfA == 0) {
#pragma unroll
                    for (int q = 0; q < 8; ++q) {
                        const float4 zv = *(const float4*)&s_z[q*4];
                        a0 = fmaf(zv.x, wf1r[q*4+0], a0);
                        a1 = fmaf(zv.y, wf1r[q*4+1], a1);
                        a2 = fmaf(zv.z, wf1r[q*4+2], a2);
                        a3 = fmaf(zv.w, wf1r[q*4+3], a3);
                    }
                } else {
#pragma unroll
                    for (int q = 0; q < 9; ++q) {
                        const float4 zv = *(const float4*)&s_z[32 + q*4];
                        a0 = fmaf(zv.x, wf1r[q*4+0], a0);
                        a1 = fmaf(zv.y, wf1r[q*4+1], a1);
                        a2 = fmaf(zv.z, wf1r[q*4+2], a2);
                        a3 = fmaf(zv.w, wf1r[q*4+3], a3);
                    }
                }
                s_part[halfA*260 + colA] = (a0+a1)+(a2+a3);
            }
            __syncthreads();
            if (t < HF) {
                float s = s_bf1[t] + s_part[t] + s_part[260 + t];
                s_h1[t] = tanh_fast(s);
            }
            __syncthreads();
            // ---- L2: h1(256) -> h2(256), 8x16 register block
            {
                float acc0=0.f, acc1=0.f, acc2=0.f, acc3=0.f;
                float acc4=0.f, acc5=0.f, acc6=0.f, acc7=0.f;
#pragma unroll
                for (int q = 0; q < 4; ++q) {
                    const float4 zv = *(const float4*)&s_h1[k0B + q*4];
                    const float zz[4] = {zv.x, zv.y, zv.z, zv.w};
#pragma unroll
                    for (int kk = 0; kk < 4; ++kk) {
                        const float zk = zz[kk];
                        const int k = q*4 + kk;
                        acc0 = fmaf(zk, wf2r[k][0], acc0);
                        acc1 = fmaf(zk, wf2r[k][1], acc1);
                        acc2 = fmaf(zk, wf2r[k][2], acc2);
                        acc3 = fmaf(zk, wf2r[k][3], acc3);
                        acc4 = fmaf(zk, wf2r[k][4], acc4);
                        acc5 = fmaf(zk, wf2r[k][5], acc5);
                        acc6 = fmaf(zk, wf2r[k][6], acc6);
                        acc7 = fmaf(zk, wf2r[k][7], acc7);
                    }
                }
                float4* pp = (float4*)&s_part[ksB*260 + j0];
                pp[0] = make_float4(acc0, acc1, acc2, acc3);
                pp[1] = make_float4(acc4, acc5, acc6, acc7);
            }
            __syncthreads();
            if (t < HF) {
                float s = s_bf2[t];
#pragma unroll
                for (int q = 0; q < 16; ++q) s += s_part[q*260 + t];
                s_h2[t] = tanh_fast(s);
            }
            __syncthreads();
            // ---- L3: h2(256) -> k(64)
            {
                float a0=0.f, a1=0.f, a2=0.f, a3=0.f;
#pragma unroll
                for (int q = 0; q < 8; ++q) {
                    const float4 zv = *(const float4*)&s_h2[k0C + q*4];
                    a0 = fmaf(zv.x, wf3r[q*4+0], a0);
                    a1 = fmaf(zv.y, wf3r[q*4+1], a1);
                    a2 = fmaf(zv.z, wf3r[q*4+2], a2);
                    a3 = fmaf(zv.w, wf3r[q*4+3], a3);
                }
                s_part[ksC*68 + colC] = (a0+a1)+(a2+a3);
            }
            __syncthreads();
            if (t < NX) {
                float s = s_bf3[t];
#pragma unroll
                for (int q = 0; q < 8; ++q) s += s_part[q*68 + t];
                if (ev == 0)      s_kacc[t] = s;
                else if (ev == 3) s_kacc[t] += s;
                else              s_kacc[t] += 2.0f * s;
                if (ev < 3) {
                    const float c = (ev == 2) ? DTC : 0.5f*DTC;
                    s_z[t] = s_X[t] + c * s;   // z for next k-eval
                }
            }
            __syncthreads();
        }

        // ================= state update + output =================
        if (t < NX) {
            const float xn = s_X[t] + (DTC/6.0f)*s_kacc[t] + s_g[t]*s_dw[p][t];
            s_X[t] = xn;
            outB[t*NT + st] = xn;            // out[b, t_ch, st]
            s_dw[p^1][t] = pf_dw;            // commit prefetched dW(st+1)
        }
        if (t < NS) s_u[p^1][t] = pf_u;
        __syncthreads();
    }
}

} // namespace

extern "C" void kernel_launch(void* const* d_in, const int* in_sizes, int n_in,
                              void* d_out, int out_size, void* d_ws, size_t ws_size,
                              hipStream_t stream)
{
    const float* Inputs = (const float*)d_in[0];
    const float* noise  = (const float*)d_in[1];
    // d_in[2] = t0 (unused by the reference)
    const float* Wf1 = (const float*)d_in[3];
    const float* bf1 = (const float*)d_in[4];
    const float* Wf2 = (const float*)d_in[5];
    const float* bf2 = (const float*)d_in[6];
    const float* Wf3 = (const float*)d_in[7];
    const float* bf3 = (const float*)d_in[8];
    const float* Wg1 = (const float*)d_in[9];
    const float* bg1 = (const float*)d_in[10];
    const float* Wg2 = (const float*)d_in[11];
    const float* bg2 = (const float*)d_in[12];
    float* out = (float*)d_out;

    sde_rk4_kernel<<<dim3(NB), dim3(TPB), 0, stream>>>(
        Inputs, noise, Wf1, bf1, Wf2, bf2, Wf3, bf3, Wg1, bg1, Wg2, bg2, out);
}

// Round 2
// 7953.968 us; speedup vs baseline: 1.2750x; 1.2750x over previous
//
#include <hip/hip_runtime.h>
#include <math.h>

namespace {

constexpr int TPB  = 512;
constexpr int NB   = 256;   // batch
constexpr int NT   = 1000;  // time steps
constexpr int NX   = 64;    // state dim
constexpr int NS   = 4;     // control dim
constexpr int DIN  = 68;    // NX + NS
constexpr int HF   = 256;
constexpr int HG   = 128;
constexpr float DTC   = 0.01f;
constexpr float SIGMA = 0.1f;

constexpr int HPAD  = 288;  // padded h storage: idx + (idx>>5)*4, max 283
constexpr int WG1LD = 132;  // s_wg1 row stride (bank-decorrelated)
constexpr int WG2LD = 65;   // s_wg2 row stride
constexpr int CH    = 68;   // dW/out chunk row stride (16B-aligned rows, conflict-free)

__device__ __forceinline__ int pmap(int i){ return i + ((i>>5)<<2); }

__device__ __forceinline__ float tanh_fast(float x){
    float e = __expf(2.0f*x);
    return 1.0f - 2.0f/(e+1.0f);
}
__device__ __forceinline__ float softplus_f(float x){
    return fmaxf(x,0.0f) + log1pf(__expf(-fabsf(x)));
}

// One workgroup = one batch element for all 1000 steps. 12 barriers/step.
// Every GEMV: K-split over adjacent lanes -> shuffle reduce (no LDS partials).
__global__ __launch_bounds__(TPB, 2) void sde_rk4_kernel(
    const float* __restrict__ gIn, const float* __restrict__ gNz,
    const float* __restrict__ Wf1, const float* __restrict__ bf1,
    const float* __restrict__ Wf2, const float* __restrict__ bf2,
    const float* __restrict__ Wf3, const float* __restrict__ bf3,
    const float* __restrict__ Wg1, const float* __restrict__ bg1,
    const float* __restrict__ Wg2, const float* __restrict__ bg2,
    float* __restrict__ gOut)
{
    const int b = blockIdx.x;
    const int t = threadIdx.x;

    __shared__ __align__(16) float s_z[72];        // [X(64), u(4), pad(4)]
    __shared__ __align__(16) float s_h1[HPAD];
    __shared__ __align__(16) float s_h2[HPAD];
    __shared__ __align__(16) float s_hg[HG];
    __shared__ __align__(16) float s_uall[4008];   // u[step][4]
    __shared__ __align__(16) float s_dwc[NX*CH];   // dW chunk [x][64]
    __shared__ __align__(16) float s_out[NX*CH];   // out buffer [x][64]
    __shared__ __align__(16) float s_wg1[DIN*WG1LD];
    __shared__ __align__(16) float s_wg2[HG*WG2LD];

    // ---- thread roles ----
    // L1: cols {2gA,2gA+1}, K-split 4 (slices 16/16/16/20), partners xor 1,2
    const int gA = t>>2, sA = t&3;  const int cA0 = 2*gA;  const int k0A = 16*sA;
    const int lenA = (sA==3)?20:16;
    // L2: cols {4gB..4gB+3}, K-split 8 (32 each), partners xor 1,2,4
    const int gB = t>>3, sB = t&7;  const int cB0 = 4*gB;  const int k0B = 32*sB;
    // L3 / G2 / state-owner: col cC, K-split 8
    const int cC = t>>3, sC = t&7;  const int k0C = 32*sC; const int k0H = 16*sC;
    // G1: col cG (0..127), K-split 4 (17 each), partners xor 1,2
    const int cG = t>>2;            const int k0G = 17*sA;
    const bool owner = (sC==0);     // t%8==0 : holds X, kacc, g for col cC
    const int rD = t>>3, j0D = (t&7)*8;  // chunk load/flush roles

    // ---- F-weights -> registers (zero-padded slices) ----
    float wf1r[20][2];
#pragma unroll
    for (int k=0;k<20;++k){
        const int kk = k0A + k;
        float2 wv = make_float2(0.f,0.f);
        if (k < lenA) wv = *(const float2*)&Wf1[kk*HF + cA0];
        wf1r[k][0] = wv.x; wf1r[k][1] = wv.y;
    }
    float wf2r[32][4];
#pragma unroll
    for (int k=0;k<32;++k){
        const float4 wv = *(const float4*)&Wf2[(size_t)(k0B+k)*HF + cB0];
        wf2r[k][0]=wv.x; wf2r[k][1]=wv.y; wf2r[k][2]=wv.z; wf2r[k][3]=wv.w;
    }
    float wf3r[32];
#pragma unroll
    for (int k=0;k<32;++k) wf3r[k] = Wf3[(k0C+k)*NX + cC];

    // biases (per writer/owner role)
    const float2 bf1v = *(const float2*)&bf1[cA0];
    const float4 bf2v = *(const float4*)&bf2[cB0];
    const float bf3c = bf3[cC];
    const float bg1c = bg1[cG];
    const float bg2c = bg2[cC];

    const float sq = sqrtf(DTC);
    const float* inB = gIn + (size_t)b*DIN*NT;
    const float* nzB = gNz + (size_t)b*NX*NT;
    float*      outB = gOut + (size_t)b*NX*NT;

    // ---- G-weights -> LDS (padded strides), u sequence -> LDS ----
    for (int i=t;i<DIN*HG;i+=TPB){ const int k=i>>7, c=i&(HG-1); s_wg1[k*WG1LD+c] = Wg1[i]; }
    for (int i=t;i<HG*NX; i+=TPB){ const int k=i>>6, c=i&(NX-1); s_wg2[k*WG2LD+c] = Wg2[i]; }
    for (int i=t;i<NS*NT; i+=TPB) s_uall[i] = inB[(i&3)*NT + (i>>2)];
    if (t<8)            s_uall[NS*NT+t] = 0.f;
    if (t>=68 && t<72)  s_z[t] = 0.f;           // z pad
    if (t<4)            s_z[64+t] = inB[t*NT];  // u(0)
    float X=0.f, kacc=0.f, gc=0.f;
    if (owner){ X = inB[(size_t)(NS+cC)*NT]; s_z[cC] = X; }
    __syncthreads();

    // ---------- phase lambdas ----------
    auto phaseA = [&](bool withG){
        float a00=0.f,a01=0.f,a10=0.f,a11=0.f;
#pragma unroll
        for (int q=0;q<5;++q){
            const float4 zv = *(const float4*)&s_z[k0A + 4*q];
            a00 = fmaf(zv.x, wf1r[4*q+0][0], a00);
            a10 = fmaf(zv.x, wf1r[4*q+0][1], a10);
            a01 = fmaf(zv.y, wf1r[4*q+1][0], a01);
            a11 = fmaf(zv.y, wf1r[4*q+1][1], a11);
            a00 = fmaf(zv.z, wf1r[4*q+2][0], a00);
            a10 = fmaf(zv.z, wf1r[4*q+2][1], a10);
            a01 = fmaf(zv.w, wf1r[4*q+3][0], a01);
            a11 = fmaf(zv.w, wf1r[4*q+3][1], a11);
        }
        float p0 = a00+a01, p1 = a10+a11;
        p0 += __shfl_xor(p0,1); p0 += __shfl_xor(p0,2);
        p1 += __shfl_xor(p1,1); p1 += __shfl_xor(p1,2);
        float q0 = 0.f;
        if (withG){
#pragma unroll
            for (int k=0;k<17;++k)
                q0 = fmaf(s_z[k0G+k], s_wg1[(k0G+k)*WG1LD + cG], q0);
            q0 += __shfl_xor(q0,1); q0 += __shfl_xor(q0,2);
        }
        if (sA==0){
            float2 hv;
            hv.x = tanh_fast(p0 + bf1v.x);
            hv.y = tanh_fast(p1 + bf1v.y);
            *(float2*)&s_h1[pmap(cA0)] = hv;
            if (withG) s_hg[cG] = tanh_fast(q0 + bg1c);
        }
        __syncthreads();
    };

    auto phaseB = [&](bool withG){
        float c0=0.f,c1=0.f,c2=0.f,c3=0.f;
        const float* h1p = &s_h1[36*sB];     // pmap(32*sB + j) = 36*sB + j
#pragma unroll
        for (int q=0;q<8;++q){
            const float4 hv = *(const float4*)&h1p[4*q];
            c0 = fmaf(hv.x, wf2r[4*q+0][0], c0);
            c1 = fmaf(hv.x, wf2r[4*q+0][1], c1);
            c2 = fmaf(hv.x, wf2r[4*q+0][2], c2);
            c3 = fmaf(hv.x, wf2r[4*q+0][3], c3);
            c0 = fmaf(hv.y, wf2r[4*q+1][0], c0);
            c1 = fmaf(hv.y, wf2r[4*q+1][1], c1);
            c2 = fmaf(hv.y, wf2r[4*q+1][2], c2);
            c3 = fmaf(hv.y, wf2r[4*q+1][3], c3);
            c0 = fmaf(hv.z, wf2r[4*q+2][0], c0);
            c1 = fmaf(hv.z, wf2r[4*q+2][1], c1);
            c2 = fmaf(hv.z, wf2r[4*q+2][2], c2);
            c3 = fmaf(hv.z, wf2r[4*q+2][3], c3);
            c0 = fmaf(hv.w, wf2r[4*q+3][0], c0);
            c1 = fmaf(hv.w, wf2r[4*q+3][1], c1);
            c2 = fmaf(hv.w, wf2r[4*q+3][2], c2);
            c3 = fmaf(hv.w, wf2r[4*q+3][3], c3);
        }
        c0 += __shfl_xor(c0,1); c0 += __shfl_xor(c0,2); c0 += __shfl_xor(c0,4);
        c1 += __shfl_xor(c1,1); c1 += __shfl_xor(c1,2); c1 += __shfl_xor(c1,4);
        c2 += __shfl_xor(c2,1); c2 += __shfl_xor(c2,2); c2 += __shfl_xor(c2,4);
        c3 += __shfl_xor(c3,1); c3 += __shfl_xor(c3,2); c3 += __shfl_xor(c3,4);
        float gq=0.f;
        if (withG){
#pragma unroll
            for (int k=0;k<16;++k)
                gq = fmaf(s_hg[k0H+k], s_wg2[(k0H+k)*WG2LD + cC], gq);
            gq += __shfl_xor(gq,1); gq += __shfl_xor(gq,2); gq += __shfl_xor(gq,4);
        }
        if (sB==0){
            float4 hv;
            hv.x = tanh_fast(c0 + bf2v.x);
            hv.y = tanh_fast(c1 + bf2v.y);
            hv.z = tanh_fast(c2 + bf2v.z);
            hv.w = tanh_fast(c3 + bf2v.w);
            *(float4*)&s_h2[pmap(cB0)] = hv;
        }
        if (withG && owner) gc = SIGMA*softplus_f(gq + bg2c);
        __syncthreads();
    };

    auto phaseC = [&](int ev, int st){
        float e0=0.f,e1=0.f;
        const float* h2p = &s_h2[36*sC];
#pragma unroll
        for (int q=0;q<8;++q){
            const float4 hv = *(const float4*)&h2p[4*q];
            e0 = fmaf(hv.x, wf3r[4*q+0], e0);
            e1 = fmaf(hv.y, wf3r[4*q+1], e1);
            e0 = fmaf(hv.z, wf3r[4*q+2], e0);
            e1 = fmaf(hv.w, wf3r[4*q+3], e1);
        }
        float ks = e0+e1;
        ks += __shfl_xor(ks,1); ks += __shfl_xor(ks,2); ks += __shfl_xor(ks,4);
        if (owner){
            const float kv = ks + bf3c;
            if (ev==0)      kacc = kv;
            else if (ev==3) kacc += kv;
            else            kacc += 2.0f*kv;
            if (ev<3){
                s_z[cC] = fmaf((ev==2)?DTC:0.5f*DTC, kv, X);
            } else {
                const int jj = st & 63;
                const float dw = s_dwc[cC*CH + jj];
                X = X + (DTC/6.0f)*kacc + gc*dw;
                s_z[cC] = X;
                s_out[cC*CH + jj] = X;
                if (cC < NS) s_z[64+cC] = s_uall[(st+1)*4 + cC];
            }
        }
        __syncthreads();
    };

    // ---------- main loop ----------
#pragma unroll 1
    for (int st=0; st<NT; ++st){
        if ((st & 63) == 0){
            // bulk-load next 64 steps of dW (coalesced float4), scale by sqrt(dt)
            if (st + 64 <= NT){
                const float4 v0 = *(const float4*)&nzB[(size_t)rD*NT + st + j0D];
                const float4 v1 = *(const float4*)&nzB[(size_t)rD*NT + st + j0D + 4];
                float* d = &s_dwc[rD*CH + j0D];
                d[0]=v0.x*sq; d[1]=v0.y*sq; d[2]=v0.z*sq; d[3]=v0.w*sq;
                d[4]=v1.x*sq; d[5]=v1.y*sq; d[6]=v1.z*sq; d[7]=v1.w*sq;
            } else {
#pragma unroll
                for (int e=0;e<8;++e){
                    const int j = j0D + e;
                    const float v = (st + j < NT) ? nzB[(size_t)rD*NT + st + j] : 0.f;
                    s_dwc[rD*CH + j] = v*sq;
                }
            }
        }

        phaseA(true);  phaseB(true);  phaseC(0, st);   // ev0 + G network fused
#pragma unroll
        for (int ev=1; ev<4; ++ev){
            phaseA(false); phaseB(false); phaseC(ev, st);
        }

        const int jj = st & 63;
        if (jj == 63 || st == NT-1){
            // coalesced flush of 64 buffered steps
            const int st0 = st & ~63;
            const int cnt = st - st0 + 1;
            if (cnt == 64){
                const float4 w0 = *(const float4*)&s_out[rD*CH + j0D];
                const float4 w1 = *(const float4*)&s_out[rD*CH + j0D + 4];
                *(float4*)&outB[(size_t)rD*NT + st0 + j0D]     = w0;
                *(float4*)&outB[(size_t)rD*NT + st0 + j0D + 4] = w1;
            } else {
#pragma unroll
                for (int e=0;e<8;++e){
                    const int j = j0D + e;
                    if (j < cnt) outB[(size_t)rD*NT + st0 + j] = s_out[rD*CH + j];
                }
            }
        }
    }
}

} // namespace

extern "C" void kernel_launch(void* const* d_in, const int* in_sizes, int n_in,
                              void* d_out, int out_size, void* d_ws, size_t ws_size,
                              hipStream_t stream)
{
    const float* Inputs = (const float*)d_in[0];
    const float* noise  = (const float*)d_in[1];
    // d_in[2] = t0 (unused)
    const float* Wf1 = (const float*)d_in[3];
    const float* bf1 = (const float*)d_in[4];
    const float* Wf2 = (const float*)d_in[5];
    const float* bf2 = (const float*)d_in[6];
    const float* Wf3 = (const float*)d_in[7];
    const float* bf3 = (const float*)d_in[8];
    const float* Wg1 = (const float*)d_in[9];
    const float* bg1 = (const float*)d_in[10];
    const float* Wg2 = (const float*)d_in[11];
    const float* bg2 = (const float*)d_in[12];
    float* out = (float*)d_out;

    sde_rk4_kernel<<<dim3(NB), dim3(TPB), 0, stream>>>(
        Inputs, noise, Wf1, bf1, Wf2, bf2, Wf3, bf3, Wg1, bg1, Wg2, bg2, out);
}